// Round 7
// baseline (355.480 us; speedup 1.0000x reference)
//
#include <hip/hip_runtime.h>
#include <hip/hip_bf16.h>

typedef __attribute__((ext_vector_type(8))) short short8;
typedef __attribute__((ext_vector_type(4))) float f32x4;

__device__ __forceinline__ unsigned short f2bf(float f) {
  union { float f; unsigned u; } v; v.f = f;
  unsigned r = v.u + 0x7FFFu + ((v.u >> 16) & 1u);
  return (unsigned short)(r >> 16);
}
__device__ __forceinline__ float bf2f(unsigned short h) {
  union { unsigned u; float f; } v; v.u = ((unsigned)h) << 16;
  return v.f;
}
__device__ __forceinline__ unsigned pkbf(float a, float b) {
  __hip_bfloat162 h = __float22bfloat162_rn(float2{a, b});
  union { __hip_bfloat162 h; unsigned u; } cv; cv.h = h;
  return cv.u;
}

// ---------------- prep: cast x -> bf16 (z=0) + transpose+cast 4 weights (z=1..4) ----------------
__global__ void prep(const float* __restrict__ x, const float* __restrict__ wq,
                     const float* __restrict__ wk, const float* __restrict__ wv,
                     const float* __restrict__ wo, unsigned short* __restrict__ xb,
                     unsigned short* __restrict__ wt, unsigned short* __restrict__ wot) {
  const int z = blockIdx.z, tid = threadIdx.x;
  if (z == 0) {
    int id = blockIdx.y * 64 + blockIdx.x;  // 0..4095
#pragma unroll
    for (int rep = 0; rep < 2; ++rep) {
      int i = (rep * 4096 + id) * 256 + tid;  // 2M float4 total
      float4 v = ((const float4*)x)[i];
      ushort4 o;
      o.x = f2bf(v.x); o.y = f2bf(v.y); o.z = f2bf(v.z); o.w = f2bf(v.w);
      ((ushort4*)xb)[i] = o;
    }
    return;
  }
  __shared__ float tile[32][33];
  const float* src;
  unsigned short* dst;
  int N;
  if (z == 1) { src = wq; dst = wt; N = 2048; }
  else if (z == 2) { src = wk; dst = wt + 2048ull * 2048; N = 512; }
  else if (z == 3) { src = wv; dst = wt + 2560ull * 2048; N = 512; }
  else { src = wo; dst = wot; N = 2048; }
  const int K = 2048;
  int n0 = blockIdx.x * 32, k0 = blockIdx.y * 32;
  if (n0 >= N) return;
  int xx = tid & 31, yy = tid >> 5;  // 32 x 8
#pragma unroll
  for (int j = 0; j < 4; ++j) tile[yy + 8 * j][xx] = src[(size_t)(k0 + yy + 8 * j) * N + n0 + xx];
  __syncthreads();
#pragma unroll
  for (int j = 0; j < 4; ++j) dst[(size_t)(n0 + yy + 8 * j) * K + k0 + xx] = f2bf(tile[xx][yy + 8 * j]);
}

// ---------------- GEMM BK=64, swizzled LDS: C(MxN) = A(MxK) * Bt(NxK)^T ----------------
// MODE 0: fp32 C (ldc). MODE 1: QKV epilogue — Q cols<2048 bf16 to C, K cols [2048,2560)
// bf16 to C with fused RoPE, cols>=2560 (V) packed-b64 transposed into vt[b][kvh][d][s].
template <int MODE>
__global__ __launch_bounds__(256, 2) void gemm_bt64(const unsigned short* __restrict__ A,
                                                    const unsigned short* __restrict__ Bt,
                                                    void* __restrict__ Cv, int K, int ldc,
                                                    unsigned short* __restrict__ vt,
                                                    const float* __restrict__ fcos,
                                                    const float* __restrict__ fsin) {
  __shared__ alignas(16) unsigned short As[128 * 64];
  __shared__ alignas(16) unsigned short Bs[128 * 64];
  const int t = threadIdx.x;
  const int lane = t & 63, w = t >> 6;
  const int l15 = lane & 15, quad = lane >> 4;
  const int bn0 = blockIdx.x * 128, bm0 = blockIdx.y * 128;
  const int wm = (w >> 1) * 64, wn = (w & 1) * 64;
  const unsigned short* Ab = A + (size_t)bm0 * K;
  const unsigned short* Bb = Bt + (size_t)bn0 * K;
  const int asw = l15 & 7;  // fragment-read swizzle key (row%8 == l15%8)

  f32x4 acc[4][4];
  const f32x4 zf = {0.f, 0.f, 0.f, 0.f};
#pragma unroll
  for (int i = 0; i < 4; ++i)
#pragma unroll
    for (int j = 0; j < 4; ++j) acc[i][j] = zf;

  for (int k0 = 0; k0 < K; k0 += 64) {
    __syncthreads();
#pragma unroll
    for (int r = 0; r < 4; ++r) {
      int e = r * 256 + t;
      int row = e >> 3, cslot = e & 7;
      int cg = cslot ^ (row & 7);
      const unsigned short* ga = Ab + (size_t)row * K + k0 + cg * 8;
      __builtin_amdgcn_global_load_lds((const __attribute__((address_space(1))) void*)ga,
                                       (__attribute__((address_space(3))) void*)(As + e * 8), 16, 0, 0);
      const unsigned short* gb = Bb + (size_t)row * K + k0 + cg * 8;
      __builtin_amdgcn_global_load_lds((const __attribute__((address_space(1))) void*)gb,
                                       (__attribute__((address_space(3))) void*)(Bs + e * 8), 16, 0, 0);
    }
    __syncthreads();
#pragma unroll
    for (int s = 0; s < 2; ++s) {
      short8 af[4], bf[4];
#pragma unroll
      for (int i = 0; i < 4; ++i)
        af[i] = *reinterpret_cast<const short8*>(As + (wm + i * 16 + l15) * 64 + (((s * 4 + quad) ^ asw) * 8));
#pragma unroll
      for (int j = 0; j < 4; ++j)
        bf[j] = *reinterpret_cast<const short8*>(Bs + (wn + j * 16 + l15) * 64 + (((s * 4 + quad) ^ asw) * 8));
      __builtin_amdgcn_s_setprio(1);
#pragma unroll
      for (int i = 0; i < 4; ++i)
#pragma unroll
        for (int j = 0; j < 4; ++j)
          acc[i][j] = __builtin_amdgcn_mfma_f32_16x16x32_bf16(af[i], bf[j], acc[i][j], 0, 0, 0);
      __builtin_amdgcn_s_setprio(0);
    }
  }

  if (MODE == 1 && bn0 >= 2560) {
    // V block -> vt[b][kvh][d][s], packed 4 rows (consecutive s) per b64 store
    const int b = bm0 >> 11;
#pragma unroll
    for (int i = 0; i < 4; ++i) {
      int srow = (bm0 + wm + i * 16 + quad * 4) & 2047;
#pragma unroll
      for (int j = 0; j < 4; ++j) {
        int vcol = bn0 - 2560 + wn + j * 16 + l15;
        int kvh = vcol >> 6, d = vcol & 63;
        uint2 pk = make_uint2(pkbf(acc[i][j][0], acc[i][j][1]), pkbf(acc[i][j][2], acc[i][j][3]));
        *reinterpret_cast<uint2*>(vt + ((size_t)(b * 8 + kvh) * 64 + d) * 2048 + srow) = pk;
      }
    }
  } else if (MODE == 1 && bn0 >= 2048) {
    // K block: fused RoPE (partner element via lane^1 shuffle), then bf16 store
#pragma unroll
    for (int i = 0; i < 4; ++i)
#pragma unroll
      for (int j = 0; j < 4; ++j)
#pragma unroll
        for (int r = 0; r < 4; ++r) {
          int row = bm0 + wm + i * 16 + quad * 4 + r;
          int s = row & 2047;
          int col = bn0 + wn + j * 16 + l15;
          int fi = ((col - 2048) >> 1) & 31;
          float val = acc[i][j][r];
          float par = __shfl_xor(val, 1, 64);
          float c = fcos[s * 32 + fi], sn = fsin[s * 32 + fi];
          float o = (lane & 1) ? (par * sn + val * c) : (val * c - par * sn);
          ((unsigned short*)Cv)[(size_t)row * ldc + col] = f2bf(o);
        }
  } else {
#pragma unroll
    for (int i = 0; i < 4; ++i)
#pragma unroll
      for (int j = 0; j < 4; ++j)
#pragma unroll
        for (int r = 0; r < 4; ++r) {
          size_t row = (size_t)(bm0 + wm + i * 16 + quad * 4 + r);
          size_t col = (size_t)(bn0 + wn + j * 16 + l15);
          if (MODE == 1)
            ((unsigned short*)Cv)[row * ldc + col] = f2bf(acc[i][j][r]);
          else
            ((float*)Cv)[row * ldc + col] = acc[i][j][r];
        }
  }
}

// ---------------- flash attention: ZERO-barrier. K/V read directly from L2-resident global ----------------
// Ps is wave-private (proven: no barrier between its write and read). K slab (256KB) + V slab
// (256KB) per (b,kvh) are L2-resident; per-tile 8KB re-read by 4 waves hits L1.
// Grid (32,16,2): x -> head-slot with h=(x&7)*4+(x>>3) so each XCD serves ONE kvh (1MB hot/XCD);
// y -> qb via pairing y<8?y:23-y so each CU's resident blocks sum to constant work.
__global__ __launch_bounds__(256, 4) void flash_attn(const unsigned short* __restrict__ qkv,
                                                     const unsigned short* __restrict__ vt,
                                                     const float* __restrict__ fcos,
                                                     const float* __restrict__ fsin,
                                                     unsigned short* __restrict__ out) {
  __shared__ alignas(16) unsigned short Ps[128 * 64];
  const int t = threadIdx.x, lane = t & 63, w = t >> 6;
  const int l15 = lane & 15, quad = lane >> 4;
  const int hs = blockIdx.x;
  const int h = ((hs & 7) << 2) + (hs >> 3);  // kvh = hs&7
  const int yy = blockIdx.y;
  const int qb = (yy < 8) ? yy : 23 - yy;  // pair lengths: (2y+2)+(2(15-y)+2)=36 const per CU
  const int b = blockIdx.z;
  const int q0 = qb * 128;
  const int kvh = hs & 7;
  const size_t rowB = (size_t)b * 2048;
  const unsigned short* Qg = qkv + (rowB + q0) * 2560 + h * 64;
  const unsigned short* Kgb = qkv + rowB * 2560 + 2048 + kvh * 64;
  const unsigned short* Vgb = vt + (size_t)(b * 8 + kvh) * 64 * 2048;
  const float SC = 0.18033688011112042f;  // (1/8)*log2(e), folded into Q

  short8 qf[2][2];
#pragma unroll
  for (int mt = 0; mt < 2; ++mt)
#pragma unroll
    for (int s = 0; s < 2; ++s) {
      int qrow = w * 32 + mt * 16 + l15;
      short8 raw = *reinterpret_cast<const short8*>(Qg + (size_t)qrow * 2560 + s * 32 + quad * 8);
      f32x4 c4 = *reinterpret_cast<const f32x4*>(fcos + (size_t)(q0 + qrow) * 32 + s * 16 + quad * 4);
      f32x4 s4 = *reinterpret_cast<const f32x4*>(fsin + (size_t)(q0 + qrow) * 32 + s * 16 + quad * 4);
      short8 o;
#pragma unroll
      for (int k = 0; k < 4; ++k) {
        float xr = bf2f((unsigned short)raw[2 * k]);
        float xi = bf2f((unsigned short)raw[2 * k + 1]);
        o[2 * k] = (short)f2bf((xr * c4[k] - xi * s4[k]) * SC);
        o[2 * k + 1] = (short)f2bf((xr * s4[k] + xi * c4[k]) * SC);
      }
      qf[mt][s] = o;
    }

  const f32x4 zf = {0.f, 0.f, 0.f, 0.f};
  f32x4 oacc[2][4], lacc[2];
#pragma unroll
  for (int mt = 0; mt < 2; ++mt) {
    lacc[mt] = zf;
#pragma unroll
    for (int nt = 0; nt < 4; ++nt) oacc[mt][nt] = zf;
  }
  short8 onesf;
#pragma unroll
  for (int k = 0; k < 8; ++k) onesf[k] = (short)0x3F80;  // bf16 1.0

  const int asw = l15 & 7;
  // per-wave trip count: wave rows q0+w*32 .. +31; last tile = (q0+w*32+31)>>6
  const int kb_end = 2 * qb + 1 + (w >> 1);

  for (int kb = 0; kb < kb_end; ++kb) {
    const bool needMask = (kb * 64 + 63) > (q0 + w * 32);

#pragma unroll
    for (int kvt = 0; kvt < 4; ++kvt) {
      f32x4 st0 = zf, st1 = zf;
      const unsigned short* Kr = Kgb + (size_t)(kb * 64 + kvt * 16 + l15) * 2560;
#pragma unroll
      for (int s = 0; s < 2; ++s) {
        short8 kf = *reinterpret_cast<const short8*>(Kr + (s * 4 + quad) * 8);
        __builtin_amdgcn_s_setprio(1);
        st0 = __builtin_amdgcn_mfma_f32_16x16x32_bf16(kf, qf[0][s], st0, 0, 0, 0);
        st1 = __builtin_amdgcn_mfma_f32_16x16x32_bf16(kf, qf[1][s], st1, 0, 0, 0);
        __builtin_amdgcn_s_setprio(0);
      }
      const int pcol = ((kvt * 2 + (quad >> 1)) ^ asw) * 8 + (quad & 1) * 4;
      if (needMask) {
        const int kvb = kb * 64 + kvt * 16 + quad * 4;
#pragma unroll
        for (int qt = 0; qt < 2; ++qt) {
          const f32x4 stv = qt ? st1 : st0;
          const int qg = q0 + w * 32 + qt * 16 + l15;
          float p[4];
#pragma unroll
          for (int r = 0; r < 4; ++r) {
            float pv = __builtin_amdgcn_exp2f(stv[r]);
            p[r] = (kvb + r > qg) ? 0.f : pv;
          }
          *reinterpret_cast<uint2*>(Ps + (size_t)(w * 32 + qt * 16 + l15) * 64 + pcol) =
              make_uint2(pkbf(p[0], p[1]), pkbf(p[2], p[3]));
        }
      } else {
#pragma unroll
        for (int qt = 0; qt < 2; ++qt) {
          const f32x4 stv = qt ? st1 : st0;
          float p[4];
#pragma unroll
          for (int r = 0; r < 4; ++r) p[r] = __builtin_amdgcn_exp2f(stv[r]);
          *reinterpret_cast<uint2*>(Ps + (size_t)(w * 32 + qt * 16 + l15) * 64 + pcol) =
              make_uint2(pkbf(p[0], p[1]), pkbf(p[2], p[3]));
        }
      }
    }

#pragma unroll
    for (int s = 0; s < 2; ++s) {
      short8 vf[4];
#pragma unroll
      for (int nt = 0; nt < 4; ++nt)
        vf[nt] = *reinterpret_cast<const short8*>(Vgb + (size_t)(nt * 16 + l15) * 2048 + kb * 64 + (s * 4 + quad) * 8);
#pragma unroll
      for (int mt = 0; mt < 2; ++mt) {
        short8 pf = *reinterpret_cast<const short8*>(Ps + (size_t)(w * 32 + mt * 16 + l15) * 64 + ((s * 4 + quad) ^ asw) * 8);
        __builtin_amdgcn_s_setprio(1);
#pragma unroll
        for (int nt = 0; nt < 4; ++nt)
          oacc[mt][nt] = __builtin_amdgcn_mfma_f32_16x16x32_bf16(pf, vf[nt], oacc[mt][nt], 0, 0, 0);
        lacc[mt] = __builtin_amdgcn_mfma_f32_16x16x32_bf16(pf, onesf, lacc[mt], 0, 0, 0);
        __builtin_amdgcn_s_setprio(0);
      }
    }
  }

  // lacc[mt][r] = rowsum for q-row (quad*4+r) of tile mt — same indexing as oacc rows
  float linv[2][4];
#pragma unroll
  for (int mt = 0; mt < 2; ++mt)
#pragma unroll
    for (int r = 0; r < 4; ++r) linv[mt][r] = 1.f / lacc[mt][r];

#pragma unroll
  for (int mt = 0; mt < 2; ++mt)
#pragma unroll
    for (int nt = 0; nt < 4; ++nt)
#pragma unroll
      for (int r = 0; r < 4; ++r) {
        size_t row = rowB + (size_t)(q0 + w * 32 + mt * 16 + quad * 4 + r);
        size_t col = (size_t)h * 64 + nt * 16 + l15;
        out[row * 2048 + col] = f2bf(oacc[mt][nt][r] * linv[mt][r]);
      }
}

extern "C" void kernel_launch(void* const* d_in, const int* in_sizes, int n_in, void* d_out,
                              int out_size, void* d_ws, size_t ws_size, hipStream_t stream) {
  const float* x = (const float*)d_in[0];
  const float* fcos = (const float*)d_in[1];
  const float* fsin = (const float*)d_in[2];
  const float* wq = (const float*)d_in[3];
  const float* wk = (const float*)d_in[4];
  const float* wv = (const float*)d_in[5];
  const float* wo = (const float*)d_in[6];

  char* ws = (char*)d_ws;
  unsigned short* xb = (unsigned short*)ws;                       // 4096x2048 bf16  @0      (16 MiB)
  unsigned short* wt = (unsigned short*)(ws + 16777216ull);       // 3072x2048 bf16  @16 MiB (12 MiB)
  unsigned short* wot = (unsigned short*)(ws + 29360128ull);      // 2048x2048 bf16  @28 MiB (8 MiB)
  unsigned short* qkv = (unsigned short*)(ws + 37748736ull);      // 4096x2560 bf16  @36 MiB (20 MiB)
  unsigned short* attno = (unsigned short*)(ws + 58720256ull);    // 4096x2048 bf16  @56 MiB (16 MiB)
  unsigned short* vt = (unsigned short*)(ws + 75497472ull);       // 16x64x2048 bf16 @72 MiB (4 MiB)
  // total: 76 MiB

  prep<<<dim3(64, 64, 5), 256, 0, stream>>>(x, wq, wk, wv, wo, xb, wt, wot);
  // QKV GEMM over N=3072 concat [wq|wk|wv]; Q -> qkv, K -> qkv with fused RoPE, V -> vt transposed
  gemm_bt64<1><<<dim3(24, 32), 256, 0, stream>>>(xb, wt, qkv, 2048, 2560, vt, fcos, fsin);
  flash_attn<<<dim3(32, 16, 2), 256, 0, stream>>>(qkv, vt, fcos, fsin, attno);
  gemm_bt64<0><<<dim3(16, 32), 256, 0, stream>>>(attno, wot, d_out, 2048, 2048, nullptr, nullptr, nullptr);
}

// Round 8
// 273.166 us; speedup vs baseline: 1.3013x; 1.3013x over previous
//
#include <hip/hip_runtime.h>
#include <hip/hip_bf16.h>

typedef __attribute__((ext_vector_type(8))) short short8;
typedef __attribute__((ext_vector_type(4))) float f32x4;

__device__ __forceinline__ unsigned short f2bf(float f) {
  union { float f; unsigned u; } v; v.f = f;
  unsigned r = v.u + 0x7FFFu + ((v.u >> 16) & 1u);
  return (unsigned short)(r >> 16);
}
__device__ __forceinline__ float bf2f(unsigned short h) {
  union { unsigned u; float f; } v; v.u = ((unsigned)h) << 16;
  return v.f;
}
__device__ __forceinline__ unsigned pkbf(float a, float b) {
  __hip_bfloat162 h = __float22bfloat162_rn(float2{a, b});
  union { __hip_bfloat162 h; unsigned u; } cv; cv.h = h;
  return cv.u;
}

// ---------------- prep: cast x -> bf16 (z=0) + transpose+cast 4 weights (z=1..4) ----------------
__global__ void prep(const float* __restrict__ x, const float* __restrict__ wq,
                     const float* __restrict__ wk, const float* __restrict__ wv,
                     const float* __restrict__ wo, unsigned short* __restrict__ xb,
                     unsigned short* __restrict__ wt, unsigned short* __restrict__ wot) {
  const int z = blockIdx.z, tid = threadIdx.x;
  if (z == 0) {
    int id = blockIdx.y * 64 + blockIdx.x;  // 0..4095
#pragma unroll
    for (int rep = 0; rep < 2; ++rep) {
      int i = (rep * 4096 + id) * 256 + tid;  // 2M float4 total
      float4 v = ((const float4*)x)[i];
      ushort4 o;
      o.x = f2bf(v.x); o.y = f2bf(v.y); o.z = f2bf(v.z); o.w = f2bf(v.w);
      ((ushort4*)xb)[i] = o;
    }
    return;
  }
  __shared__ float tile[32][33];
  const float* src;
  unsigned short* dst;
  int N;
  if (z == 1) { src = wq; dst = wt; N = 2048; }
  else if (z == 2) { src = wk; dst = wt + 2048ull * 2048; N = 512; }
  else if (z == 3) { src = wv; dst = wt + 2560ull * 2048; N = 512; }
  else { src = wo; dst = wot; N = 2048; }
  const int K = 2048;
  int n0 = blockIdx.x * 32, k0 = blockIdx.y * 32;
  if (n0 >= N) return;
  int xx = tid & 31, yy = tid >> 5;  // 32 x 8
#pragma unroll
  for (int j = 0; j < 4; ++j) tile[yy + 8 * j][xx] = src[(size_t)(k0 + yy + 8 * j) * N + n0 + xx];
  __syncthreads();
#pragma unroll
  for (int j = 0; j < 4; ++j) dst[(size_t)(n0 + yy + 8 * j) * K + k0 + xx] = f2bf(tile[xx][yy + 8 * j]);
}

// ---------------- GEMM BK=64, swizzled LDS: C(MxN) = A(MxK) * Bt(NxK)^T ----------------
// MODE 0: fp32 C (ldc). MODE 1: QKV epilogue — Q cols<2048 bf16 to C, K cols [2048,2560)
// bf16 to C with fused RoPE, cols>=2560 (V) packed-b64 transposed into vt[b][kvh][d][s].
template <int MODE>
__global__ __launch_bounds__(256, 2) void gemm_bt64(const unsigned short* __restrict__ A,
                                                    const unsigned short* __restrict__ Bt,
                                                    void* __restrict__ Cv, int K, int ldc,
                                                    unsigned short* __restrict__ vt,
                                                    const float* __restrict__ fcos,
                                                    const float* __restrict__ fsin) {
  __shared__ alignas(16) unsigned short As[128 * 64];
  __shared__ alignas(16) unsigned short Bs[128 * 64];
  const int t = threadIdx.x;
  const int lane = t & 63, w = t >> 6;
  const int l15 = lane & 15, quad = lane >> 4;
  const int bn0 = blockIdx.x * 128, bm0 = blockIdx.y * 128;
  const int wm = (w >> 1) * 64, wn = (w & 1) * 64;
  const unsigned short* Ab = A + (size_t)bm0 * K;
  const unsigned short* Bb = Bt + (size_t)bn0 * K;
  const int asw = l15 & 7;  // fragment-read swizzle key (row%8 == l15%8)

  f32x4 acc[4][4];
  const f32x4 zf = {0.f, 0.f, 0.f, 0.f};
#pragma unroll
  for (int i = 0; i < 4; ++i)
#pragma unroll
    for (int j = 0; j < 4; ++j) acc[i][j] = zf;

  for (int k0 = 0; k0 < K; k0 += 64) {
    __syncthreads();
#pragma unroll
    for (int r = 0; r < 4; ++r) {
      int e = r * 256 + t;
      int row = e >> 3, cslot = e & 7;
      int cg = cslot ^ (row & 7);
      const unsigned short* ga = Ab + (size_t)row * K + k0 + cg * 8;
      __builtin_amdgcn_global_load_lds((const __attribute__((address_space(1))) void*)ga,
                                       (__attribute__((address_space(3))) void*)(As + e * 8), 16, 0, 0);
      const unsigned short* gb = Bb + (size_t)row * K + k0 + cg * 8;
      __builtin_amdgcn_global_load_lds((const __attribute__((address_space(1))) void*)gb,
                                       (__attribute__((address_space(3))) void*)(Bs + e * 8), 16, 0, 0);
    }
    __syncthreads();
#pragma unroll
    for (int s = 0; s < 2; ++s) {
      short8 af[4], bf[4];
#pragma unroll
      for (int i = 0; i < 4; ++i)
        af[i] = *reinterpret_cast<const short8*>(As + (wm + i * 16 + l15) * 64 + (((s * 4 + quad) ^ asw) * 8));
#pragma unroll
      for (int j = 0; j < 4; ++j)
        bf[j] = *reinterpret_cast<const short8*>(Bs + (wn + j * 16 + l15) * 64 + (((s * 4 + quad) ^ asw) * 8));
      __builtin_amdgcn_s_setprio(1);
#pragma unroll
      for (int i = 0; i < 4; ++i)
#pragma unroll
        for (int j = 0; j < 4; ++j)
          acc[i][j] = __builtin_amdgcn_mfma_f32_16x16x32_bf16(af[i], bf[j], acc[i][j], 0, 0, 0);
      __builtin_amdgcn_s_setprio(0);
    }
  }

  if (MODE == 1 && bn0 >= 2560) {
    // V block -> vt[b][kvh][d][s], packed 4 rows (consecutive s) per b64 store
    const int b = bm0 >> 11;
#pragma unroll
    for (int i = 0; i < 4; ++i) {
      int srow = (bm0 + wm + i * 16 + quad * 4) & 2047;
#pragma unroll
      for (int j = 0; j < 4; ++j) {
        int vcol = bn0 - 2560 + wn + j * 16 + l15;
        int kvh = vcol >> 6, d = vcol & 63;
        uint2 pk = make_uint2(pkbf(acc[i][j][0], acc[i][j][1]), pkbf(acc[i][j][2], acc[i][j][3]));
        *reinterpret_cast<uint2*>(vt + ((size_t)(b * 8 + kvh) * 64 + d) * 2048 + srow) = pk;
      }
    }
  } else if (MODE == 1 && bn0 >= 2048) {
    // K block: fused RoPE (partner element via lane^1 shuffle), then bf16 store
#pragma unroll
    for (int i = 0; i < 4; ++i)
#pragma unroll
      for (int j = 0; j < 4; ++j)
#pragma unroll
        for (int r = 0; r < 4; ++r) {
          int row = bm0 + wm + i * 16 + quad * 4 + r;
          int s = row & 2047;
          int col = bn0 + wn + j * 16 + l15;
          int fi = ((col - 2048) >> 1) & 31;
          float val = acc[i][j][r];
          float par = __shfl_xor(val, 1, 64);
          float c = fcos[s * 32 + fi], sn = fsin[s * 32 + fi];
          float o = (lane & 1) ? (par * sn + val * c) : (val * c - par * sn);
          ((unsigned short*)Cv)[(size_t)row * ldc + col] = f2bf(o);
        }
  } else {
#pragma unroll
    for (int i = 0; i < 4; ++i)
#pragma unroll
      for (int j = 0; j < 4; ++j)
#pragma unroll
        for (int r = 0; r < 4; ++r) {
          size_t row = (size_t)(bm0 + wm + i * 16 + quad * 4 + r);
          size_t col = (size_t)(bn0 + wn + j * 16 + l15);
          if (MODE == 1)
            ((unsigned short*)Cv)[row * ldc + col] = f2bf(acc[i][j][r]);
          else
            ((float*)Cv)[row * ldc + col] = acc[i][j][r];
        }
  }
}

// ---------------- flash attention: 256 q-rows/block, 8 waves x 32 rows, 64-row K/V tile ----------------
// Same proven 2-barrier loop & per-wave code as the 70.4µs kernel, but one K/V staging serves
// 8 waves (staging iters & barriers halved per unit compute). LDS 48KB -> 2 blocks/CU =
// 16 waves/CU (same residency). qb = x ^ (z?7:0): co-resident pair (c, c+256) sums to a
// constant 36 iters per CU -> deterministic drain balance.
__global__ __launch_bounds__(512, 4) void flash_attn(const unsigned short* __restrict__ qkv,
                                                     const unsigned short* __restrict__ vt,
                                                     const float* __restrict__ fcos,
                                                     const float* __restrict__ fsin,
                                                     unsigned short* __restrict__ out) {
  __shared__ alignas(16) unsigned short Ks[64 * 64];
  __shared__ alignas(16) unsigned short Vs[64 * 64];
  __shared__ alignas(16) unsigned short Ps[256 * 64];
  const int t = threadIdx.x, lane = t & 63, w = t >> 6;  // w 0..7
  const int l15 = lane & 15, quad = lane >> 4;
  const int h = blockIdx.y, b = blockIdx.z;
  const int qb = (int)blockIdx.x ^ (b ? 7 : 0);  // 0..7, paired across z
  const int q0 = qb * 256;
  const int kvh = h >> 2;
  const size_t rowB = (size_t)b * 2048;
  const unsigned short* Qg = qkv + (rowB + q0) * 2560 + h * 64;
  const unsigned short* Kg = qkv + rowB * 2560 + 2048 + kvh * 64;
  const unsigned short* Vtg = vt + (size_t)(b * 8 + kvh) * 64 * 2048;
  const float SC = 0.18033688011112042f;  // (1/8)*log2(e), folded into Q

  short8 qf[2][2];
#pragma unroll
  for (int mt = 0; mt < 2; ++mt)
#pragma unroll
    for (int s = 0; s < 2; ++s) {
      int qrow = w * 32 + mt * 16 + l15;  // 0..255
      short8 raw = *reinterpret_cast<const short8*>(Qg + (size_t)qrow * 2560 + s * 32 + quad * 8);
      f32x4 c4 = *reinterpret_cast<const f32x4*>(fcos + (size_t)(q0 + qrow) * 32 + s * 16 + quad * 4);
      f32x4 s4 = *reinterpret_cast<const f32x4*>(fsin + (size_t)(q0 + qrow) * 32 + s * 16 + quad * 4);
      short8 o;
#pragma unroll
      for (int k = 0; k < 4; ++k) {
        float xr = bf2f((unsigned short)raw[2 * k]);
        float xi = bf2f((unsigned short)raw[2 * k + 1]);
        o[2 * k] = (short)f2bf((xr * c4[k] - xi * s4[k]) * SC);
        o[2 * k + 1] = (short)f2bf((xr * s4[k] + xi * c4[k]) * SC);
      }
      qf[mt][s] = o;
    }

  const f32x4 zf = {0.f, 0.f, 0.f, 0.f};
  f32x4 oacc[2][4], lacc[2];
#pragma unroll
  for (int mt = 0; mt < 2; ++mt) {
    lacc[mt] = zf;
#pragma unroll
    for (int nt = 0; nt < 4; ++nt) oacc[mt][nt] = zf;
  }
  short8 onesf;
#pragma unroll
  for (int k = 0; k < 8; ++k) onesf[k] = (short)0x3F80;  // bf16 1.0

  const int kb_end = 4 * qb + 4;
  const int srow = t >> 3, sc8 = t & 7;  // 64 rows x 8 chunks, 1 short8 each for K and V
  const int soff = srow * 64 + ((sc8 ^ (srow & 7)) * 8);
  const int asw = l15 & 7;
  short8 kreg, vreg;
  kreg = *reinterpret_cast<const short8*>(Kg + (size_t)srow * 2560 + sc8 * 8);
  vreg = *reinterpret_cast<const short8*>(Vtg + (size_t)srow * 2048 + sc8 * 8);

  for (int kb = 0; kb < kb_end; ++kb) {
    __syncthreads();
    *reinterpret_cast<short8*>(Ks + soff) = kreg;
    *reinterpret_cast<short8*>(Vs + soff) = vreg;
    __syncthreads();
    if (kb + 1 < kb_end) {
      kreg = *reinterpret_cast<const short8*>(Kg + (size_t)((kb + 1) * 64 + srow) * 2560 + sc8 * 8);
      vreg = *reinterpret_cast<const short8*>(Vtg + (size_t)srow * 2048 + (kb + 1) * 64 + sc8 * 8);
    }
    const int qmaxw = q0 + w * 32 + 31;
    if (kb * 64 > qmaxw) continue;
    const bool needMask = (kb * 64 + 63) > (q0 + w * 32);

#pragma unroll
    for (int kvt = 0; kvt < 4; ++kvt) {
      f32x4 st0 = zf, st1 = zf;
#pragma unroll
      for (int s = 0; s < 2; ++s) {
        short8 kf = *reinterpret_cast<const short8*>(Ks + (kvt * 16 + l15) * 64 + ((s * 4 + quad) ^ asw) * 8);
        __builtin_amdgcn_s_setprio(1);
        st0 = __builtin_amdgcn_mfma_f32_16x16x32_bf16(kf, qf[0][s], st0, 0, 0, 0);
        st1 = __builtin_amdgcn_mfma_f32_16x16x32_bf16(kf, qf[1][s], st1, 0, 0, 0);
        __builtin_amdgcn_s_setprio(0);
      }
      const int pcol = ((kvt * 2 + (quad >> 1)) ^ asw) * 8 + (quad & 1) * 4;
      if (needMask) {
        const int kvb = kb * 64 + kvt * 16 + quad * 4;
#pragma unroll
        for (int qt = 0; qt < 2; ++qt) {
          const f32x4 stv = qt ? st1 : st0;
          const int qg = q0 + w * 32 + qt * 16 + l15;
          float p[4];
#pragma unroll
          for (int r = 0; r < 4; ++r) {
            float pv = __builtin_amdgcn_exp2f(stv[r]);
            p[r] = (kvb + r > qg) ? 0.f : pv;
          }
          *reinterpret_cast<uint2*>(Ps + (size_t)(w * 32 + qt * 16 + l15) * 64 + pcol) =
              make_uint2(pkbf(p[0], p[1]), pkbf(p[2], p[3]));
        }
      } else {
#pragma unroll
        for (int qt = 0; qt < 2; ++qt) {
          const f32x4 stv = qt ? st1 : st0;
          float p[4];
#pragma unroll
          for (int r = 0; r < 4; ++r) p[r] = __builtin_amdgcn_exp2f(stv[r]);
          *reinterpret_cast<uint2*>(Ps + (size_t)(w * 32 + qt * 16 + l15) * 64 + pcol) =
              make_uint2(pkbf(p[0], p[1]), pkbf(p[2], p[3]));
        }
      }
    }

#pragma unroll
    for (int s = 0; s < 2; ++s) {
      short8 vf[4];
#pragma unroll
      for (int nt = 0; nt < 4; ++nt)
        vf[nt] = *reinterpret_cast<const short8*>(Vs + (nt * 16 + l15) * 64 + ((s * 4 + quad) ^ asw) * 8);
#pragma unroll
      for (int mt = 0; mt < 2; ++mt) {
        short8 pf = *reinterpret_cast<const short8*>(Ps + (size_t)(w * 32 + mt * 16 + l15) * 64 + ((s * 4 + quad) ^ asw) * 8);
        __builtin_amdgcn_s_setprio(1);
#pragma unroll
        for (int nt = 0; nt < 4; ++nt)
          oacc[mt][nt] = __builtin_amdgcn_mfma_f32_16x16x32_bf16(pf, vf[nt], oacc[mt][nt], 0, 0, 0);
        lacc[mt] = __builtin_amdgcn_mfma_f32_16x16x32_bf16(pf, onesf, lacc[mt], 0, 0, 0);
        __builtin_amdgcn_s_setprio(0);
      }
    }
  }

  // lacc[mt][r] = rowsum for q-row (quad*4+r) of tile mt — same indexing as oacc rows
  float linv[2][4];
#pragma unroll
  for (int mt = 0; mt < 2; ++mt)
#pragma unroll
    for (int r = 0; r < 4; ++r) linv[mt][r] = 1.f / lacc[mt][r];

#pragma unroll
  for (int mt = 0; mt < 2; ++mt)
#pragma unroll
    for (int nt = 0; nt < 4; ++nt)
#pragma unroll
      for (int r = 0; r < 4; ++r) {
        size_t row = rowB + (size_t)(q0 + w * 32 + mt * 16 + quad * 4 + r);
        size_t col = (size_t)h * 64 + nt * 16 + l15;
        out[row * 2048 + col] = f2bf(oacc[mt][nt][r] * linv[mt][r]);
      }
}

extern "C" void kernel_launch(void* const* d_in, const int* in_sizes, int n_in, void* d_out,
                              int out_size, void* d_ws, size_t ws_size, hipStream_t stream) {
  const float* x = (const float*)d_in[0];
  const float* fcos = (const float*)d_in[1];
  const float* fsin = (const float*)d_in[2];
  const float* wq = (const float*)d_in[3];
  const float* wk = (const float*)d_in[4];
  const float* wv = (const float*)d_in[5];
  const float* wo = (const float*)d_in[6];

  char* ws = (char*)d_ws;
  unsigned short* xb = (unsigned short*)ws;                       // 4096x2048 bf16  @0      (16 MiB)
  unsigned short* wt = (unsigned short*)(ws + 16777216ull);       // 3072x2048 bf16  @16 MiB (12 MiB)
  unsigned short* wot = (unsigned short*)(ws + 29360128ull);      // 2048x2048 bf16  @28 MiB (8 MiB)
  unsigned short* qkv = (unsigned short*)(ws + 37748736ull);      // 4096x2560 bf16  @36 MiB (20 MiB)
  unsigned short* attno = (unsigned short*)(ws + 58720256ull);    // 4096x2048 bf16  @56 MiB (16 MiB)
  unsigned short* vt = (unsigned short*)(ws + 75497472ull);       // 16x64x2048 bf16 @72 MiB (4 MiB)
  // total: 76 MiB

  prep<<<dim3(64, 64, 5), 256, 0, stream>>>(x, wq, wk, wv, wo, xb, wt, wot);
  // QKV GEMM over N=3072 concat [wq|wk|wv]; Q -> qkv, K -> qkv with fused RoPE, V -> vt transposed
  gemm_bt64<1><<<dim3(24, 32), 256, 0, stream>>>(xb, wt, qkv, 2048, 2560, vt, fcos, fsin);
  flash_attn<<<dim3(8, 32, 2), 512, 0, stream>>>(qkv, vt, fcos, fsin, attno);
  gemm_bt64<0><<<dim3(16, 32), 256, 0, stream>>>(attno, wot, d_out, 2048, 2048, nullptr, nullptr, nullptr);
}

// Round 9
// 265.487 us; speedup vs baseline: 1.3390x; 1.0289x over previous
//
#include <hip/hip_runtime.h>
#include <hip/hip_bf16.h>

typedef __attribute__((ext_vector_type(8))) short short8;
typedef __attribute__((ext_vector_type(4))) float f32x4;

__device__ __forceinline__ unsigned short f2bf(float f) {
  union { float f; unsigned u; } v; v.f = f;
  unsigned r = v.u + 0x7FFFu + ((v.u >> 16) & 1u);
  return (unsigned short)(r >> 16);
}
__device__ __forceinline__ float bf2f(unsigned short h) {
  union { unsigned u; float f; } v; v.u = ((unsigned)h) << 16;
  return v.f;
}
__device__ __forceinline__ unsigned pkbf(float a, float b) {
  __hip_bfloat162 h = __float22bfloat162_rn(float2{a, b});
  union { __hip_bfloat162 h; unsigned u; } cv; cv.h = h;
  return cv.u;
}

// ---------------- prep: cast x -> bf16 (z=0) + transpose+cast 4 weights (z=1..4) ----------------
__global__ void prep(const float* __restrict__ x, const float* __restrict__ wq,
                     const float* __restrict__ wk, const float* __restrict__ wv,
                     const float* __restrict__ wo, unsigned short* __restrict__ xb,
                     unsigned short* __restrict__ wt, unsigned short* __restrict__ wot) {
  const int z = blockIdx.z, tid = threadIdx.x;
  if (z == 0) {
    int id = blockIdx.y * 64 + blockIdx.x;  // 0..4095
#pragma unroll
    for (int rep = 0; rep < 2; ++rep) {
      int i = (rep * 4096 + id) * 256 + tid;  // 2M float4 total
      float4 v = ((const float4*)x)[i];
      ushort4 o;
      o.x = f2bf(v.x); o.y = f2bf(v.y); o.z = f2bf(v.z); o.w = f2bf(v.w);
      ((ushort4*)xb)[i] = o;
    }
    return;
  }
  __shared__ float tile[32][33];
  const float* src;
  unsigned short* dst;
  int N;
  if (z == 1) { src = wq; dst = wt; N = 2048; }
  else if (z == 2) { src = wk; dst = wt + 2048ull * 2048; N = 512; }
  else if (z == 3) { src = wv; dst = wt + 2560ull * 2048; N = 512; }
  else { src = wo; dst = wot; N = 2048; }
  const int K = 2048;
  int n0 = blockIdx.x * 32, k0 = blockIdx.y * 32;
  if (n0 >= N) return;
  int xx = tid & 31, yy = tid >> 5;  // 32 x 8
#pragma unroll
  for (int j = 0; j < 4; ++j) tile[yy + 8 * j][xx] = src[(size_t)(k0 + yy + 8 * j) * N + n0 + xx];
  __syncthreads();
#pragma unroll
  for (int j = 0; j < 4; ++j) dst[(size_t)(n0 + yy + 8 * j) * K + k0 + xx] = f2bf(tile[xx][yy + 8 * j]);
}

// ---------------- GEMM BK=64, swizzled LDS: C(MxN) = A(MxK) * Bt(NxK)^T ----------------
// MODE 0: fp32 C (ldc). MODE 1: QKV epilogue — Q cols<2048 bf16 to C, K cols [2048,2560)
// bf16 to C with fused RoPE, cols>=2560 (V) packed-b64 transposed into vt[b][kvh][d][s].
template <int MODE>
__global__ __launch_bounds__(256, 2) void gemm_bt64(const unsigned short* __restrict__ A,
                                                    const unsigned short* __restrict__ Bt,
                                                    void* __restrict__ Cv, int K, int ldc,
                                                    unsigned short* __restrict__ vt,
                                                    const float* __restrict__ fcos,
                                                    const float* __restrict__ fsin) {
  __shared__ alignas(16) unsigned short As[128 * 64];
  __shared__ alignas(16) unsigned short Bs[128 * 64];
  const int t = threadIdx.x;
  const int lane = t & 63, w = t >> 6;
  const int l15 = lane & 15, quad = lane >> 4;
  const int bn0 = blockIdx.x * 128, bm0 = blockIdx.y * 128;
  const int wm = (w >> 1) * 64, wn = (w & 1) * 64;
  const unsigned short* Ab = A + (size_t)bm0 * K;
  const unsigned short* Bb = Bt + (size_t)bn0 * K;
  const int asw = l15 & 7;  // fragment-read swizzle key (row%8 == l15%8)

  f32x4 acc[4][4];
  const f32x4 zf = {0.f, 0.f, 0.f, 0.f};
#pragma unroll
  for (int i = 0; i < 4; ++i)
#pragma unroll
    for (int j = 0; j < 4; ++j) acc[i][j] = zf;

  for (int k0 = 0; k0 < K; k0 += 64) {
    __syncthreads();
#pragma unroll
    for (int r = 0; r < 4; ++r) {
      int e = r * 256 + t;
      int row = e >> 3, cslot = e & 7;
      int cg = cslot ^ (row & 7);
      const unsigned short* ga = Ab + (size_t)row * K + k0 + cg * 8;
      __builtin_amdgcn_global_load_lds((const __attribute__((address_space(1))) void*)ga,
                                       (__attribute__((address_space(3))) void*)(As + e * 8), 16, 0, 0);
      const unsigned short* gb = Bb + (size_t)row * K + k0 + cg * 8;
      __builtin_amdgcn_global_load_lds((const __attribute__((address_space(1))) void*)gb,
                                       (__attribute__((address_space(3))) void*)(Bs + e * 8), 16, 0, 0);
    }
    __syncthreads();
#pragma unroll
    for (int s = 0; s < 2; ++s) {
      short8 af[4], bf[4];
#pragma unroll
      for (int i = 0; i < 4; ++i)
        af[i] = *reinterpret_cast<const short8*>(As + (wm + i * 16 + l15) * 64 + (((s * 4 + quad) ^ asw) * 8));
#pragma unroll
      for (int j = 0; j < 4; ++j)
        bf[j] = *reinterpret_cast<const short8*>(Bs + (wn + j * 16 + l15) * 64 + (((s * 4 + quad) ^ asw) * 8));
      __builtin_amdgcn_s_setprio(1);
#pragma unroll
      for (int i = 0; i < 4; ++i)
#pragma unroll
        for (int j = 0; j < 4; ++j)
          acc[i][j] = __builtin_amdgcn_mfma_f32_16x16x32_bf16(af[i], bf[j], acc[i][j], 0, 0, 0);
      __builtin_amdgcn_s_setprio(0);
    }
  }

  if (MODE == 1 && bn0 >= 2560) {
    // V block -> vt[b][kvh][d][s], packed 4 rows (consecutive s) per b64 store
    const int b = bm0 >> 11;
#pragma unroll
    for (int i = 0; i < 4; ++i) {
      int srow = (bm0 + wm + i * 16 + quad * 4) & 2047;
#pragma unroll
      for (int j = 0; j < 4; ++j) {
        int vcol = bn0 - 2560 + wn + j * 16 + l15;
        int kvh = vcol >> 6, d = vcol & 63;
        uint2 pk = make_uint2(pkbf(acc[i][j][0], acc[i][j][1]), pkbf(acc[i][j][2], acc[i][j][3]));
        *reinterpret_cast<uint2*>(vt + ((size_t)(b * 8 + kvh) * 64 + d) * 2048 + srow) = pk;
      }
    }
  } else if (MODE == 1 && bn0 >= 2048) {
    // K block: fused RoPE (partner element via lane^1 shuffle), then bf16 store
#pragma unroll
    for (int i = 0; i < 4; ++i)
#pragma unroll
      for (int j = 0; j < 4; ++j)
#pragma unroll
        for (int r = 0; r < 4; ++r) {
          int row = bm0 + wm + i * 16 + quad * 4 + r;
          int s = row & 2047;
          int col = bn0 + wn + j * 16 + l15;
          int fi = ((col - 2048) >> 1) & 31;
          float val = acc[i][j][r];
          float par = __shfl_xor(val, 1, 64);
          float c = fcos[s * 32 + fi], sn = fsin[s * 32 + fi];
          float o = (lane & 1) ? (par * sn + val * c) : (val * c - par * sn);
          ((unsigned short*)Cv)[(size_t)row * ldc + col] = f2bf(o);
        }
  } else {
#pragma unroll
    for (int i = 0; i < 4; ++i)
#pragma unroll
      for (int j = 0; j < 4; ++j)
#pragma unroll
        for (int r = 0; r < 4; ++r) {
          size_t row = (size_t)(bm0 + wm + i * 16 + quad * 4 + r);
          size_t col = (size_t)(bn0 + wn + j * 16 + l15);
          if (MODE == 1)
            ((unsigned short*)Cv)[row * ldc + col] = f2bf(acc[i][j][r]);
          else
            ((float*)Cv)[row * ldc + col] = acc[i][j][r];
        }
  }
}

// ---------------- flash attention: 256 q-rows/block, 8 waves x 32 rows, 64-row K/V tile ----------------
// R8 structure + async staging: K/V staged via global_load_lds (pre-swizzled SOURCE, lane-linear
// LDS dest — R1-validated pattern), double-buffered, ONE __syncthreads per kb (drains vmcnt:
// buf[cur] ready AND all reads of buf[cur^1] finished). LDS 64KB -> still 2 blocks/CU.
__global__ __launch_bounds__(512, 4) void flash_attn(const unsigned short* __restrict__ qkv,
                                                     const unsigned short* __restrict__ vt,
                                                     const float* __restrict__ fcos,
                                                     const float* __restrict__ fsin,
                                                     unsigned short* __restrict__ out) {
  __shared__ alignas(16) unsigned short Ks[2][64 * 64];
  __shared__ alignas(16) unsigned short Vs[2][64 * 64];
  __shared__ alignas(16) unsigned short Ps[256 * 64];
  const int t = threadIdx.x, lane = t & 63, w = t >> 6;  // w 0..7
  const int l15 = lane & 15, quad = lane >> 4;
  const int h = blockIdx.y, b = blockIdx.z;
  const int qb = (int)blockIdx.x ^ (b ? 7 : 0);  // 0..7, paired across z
  const int q0 = qb * 256;
  const int kvh = h >> 2;
  const size_t rowB = (size_t)b * 2048;
  const unsigned short* Qg = qkv + (rowB + q0) * 2560 + h * 64;
  const unsigned short* Kg = qkv + rowB * 2560 + 2048 + kvh * 64;
  const unsigned short* Vtg = vt + (size_t)(b * 8 + kvh) * 64 * 2048;
  const float SC = 0.18033688011112042f;  // (1/8)*log2(e), folded into Q

  short8 qf[2][2];
#pragma unroll
  for (int mt = 0; mt < 2; ++mt)
#pragma unroll
    for (int s = 0; s < 2; ++s) {
      int qrow = w * 32 + mt * 16 + l15;  // 0..255
      short8 raw = *reinterpret_cast<const short8*>(Qg + (size_t)qrow * 2560 + s * 32 + quad * 8);
      f32x4 c4 = *reinterpret_cast<const f32x4*>(fcos + (size_t)(q0 + qrow) * 32 + s * 16 + quad * 4);
      f32x4 s4 = *reinterpret_cast<const f32x4*>(fsin + (size_t)(q0 + qrow) * 32 + s * 16 + quad * 4);
      short8 o;
#pragma unroll
      for (int k = 0; k < 4; ++k) {
        float xr = bf2f((unsigned short)raw[2 * k]);
        float xi = bf2f((unsigned short)raw[2 * k + 1]);
        o[2 * k] = (short)f2bf((xr * c4[k] - xi * s4[k]) * SC);
        o[2 * k + 1] = (short)f2bf((xr * s4[k] + xi * c4[k]) * SC);
      }
      qf[mt][s] = o;
    }

  const f32x4 zf = {0.f, 0.f, 0.f, 0.f};
  f32x4 oacc[2][4], lacc[2];
#pragma unroll
  for (int mt = 0; mt < 2; ++mt) {
    lacc[mt] = zf;
#pragma unroll
    for (int nt = 0; nt < 4; ++nt) oacc[mt][nt] = zf;
  }
  short8 onesf;
#pragma unroll
  for (int k = 0; k < 8; ++k) onesf[k] = (short)0x3F80;  // bf16 1.0

  const int kb_end = 4 * qb + 4;
  const int srow = t >> 3, sc8 = t & 7;  // 64 rows x 8 chunks: exactly 512 chunks per operand
  const int cg = sc8 ^ (srow & 7);       // pre-swizzled SOURCE chunk -> lane-linear LDS dest
  const int asw = l15 & 7;
  unsigned short* Ks0 = &Ks[0][0];
  unsigned short* Ks1 = &Ks[1][0];
  unsigned short* Vs0 = &Vs[0][0];
  unsigned short* Vs1 = &Vs[1][0];

  auto stage = [&](int buf, int kb) {
    unsigned short* kd = buf ? Ks1 : Ks0;
    unsigned short* vd = buf ? Vs1 : Vs0;
    const unsigned short* gk = Kg + (size_t)(kb * 64 + srow) * 2560 + cg * 8;
    __builtin_amdgcn_global_load_lds((const __attribute__((address_space(1))) void*)gk,
                                     (__attribute__((address_space(3))) void*)(kd + t * 8), 16, 0, 0);
    const unsigned short* gv = Vtg + (size_t)srow * 2048 + kb * 64 + cg * 8;
    __builtin_amdgcn_global_load_lds((const __attribute__((address_space(1))) void*)gv,
                                     (__attribute__((address_space(3))) void*)(vd + t * 8), 16, 0, 0);
  };

  stage(0, 0);

  for (int kb = 0; kb < kb_end; ++kb) {
    const int cur = kb & 1;
    __syncthreads();  // drains vmcnt: buf[cur] ready; all reads of buf[cur^1] from kb-1 done
    if (kb + 1 < kb_end) stage(cur ^ 1, kb + 1);
    const unsigned short* Kc = cur ? Ks1 : Ks0;
    const unsigned short* Vc = cur ? Vs1 : Vs0;
    const int qmaxw = q0 + w * 32 + 31;
    if (kb * 64 > qmaxw) continue;
    const bool needMask = (kb * 64 + 63) > (q0 + w * 32);

#pragma unroll
    for (int kvt = 0; kvt < 4; ++kvt) {
      f32x4 st0 = zf, st1 = zf;
#pragma unroll
      for (int s = 0; s < 2; ++s) {
        short8 kf = *reinterpret_cast<const short8*>(Kc + (kvt * 16 + l15) * 64 + ((s * 4 + quad) ^ asw) * 8);
        __builtin_amdgcn_s_setprio(1);
        st0 = __builtin_amdgcn_mfma_f32_16x16x32_bf16(kf, qf[0][s], st0, 0, 0, 0);
        st1 = __builtin_amdgcn_mfma_f32_16x16x32_bf16(kf, qf[1][s], st1, 0, 0, 0);
        __builtin_amdgcn_s_setprio(0);
      }
      const int pcol = ((kvt * 2 + (quad >> 1)) ^ asw) * 8 + (quad & 1) * 4;
      if (needMask) {
        const int kvb = kb * 64 + kvt * 16 + quad * 4;
#pragma unroll
        for (int qt = 0; qt < 2; ++qt) {
          const f32x4 stv = qt ? st1 : st0;
          const int qg = q0 + w * 32 + qt * 16 + l15;
          float p[4];
#pragma unroll
          for (int r = 0; r < 4; ++r) {
            float pv = __builtin_amdgcn_exp2f(stv[r]);
            p[r] = (kvb + r > qg) ? 0.f : pv;
          }
          *reinterpret_cast<uint2*>(Ps + (size_t)(w * 32 + qt * 16 + l15) * 64 + pcol) =
              make_uint2(pkbf(p[0], p[1]), pkbf(p[2], p[3]));
        }
      } else {
#pragma unroll
        for (int qt = 0; qt < 2; ++qt) {
          const f32x4 stv = qt ? st1 : st0;
          float p[4];
#pragma unroll
          for (int r = 0; r < 4; ++r) p[r] = __builtin_amdgcn_exp2f(stv[r]);
          *reinterpret_cast<uint2*>(Ps + (size_t)(w * 32 + qt * 16 + l15) * 64 + pcol) =
              make_uint2(pkbf(p[0], p[1]), pkbf(p[2], p[3]));
        }
      }
    }

#pragma unroll
    for (int s = 0; s < 2; ++s) {
      short8 vf[4];
#pragma unroll
      for (int nt = 0; nt < 4; ++nt)
        vf[nt] = *reinterpret_cast<const short8*>(Vc + (nt * 16 + l15) * 64 + ((s * 4 + quad) ^ asw) * 8);
#pragma unroll
      for (int mt = 0; mt < 2; ++mt) {
        short8 pf = *reinterpret_cast<const short8*>(Ps + (size_t)(w * 32 + mt * 16 + l15) * 64 + ((s * 4 + quad) ^ asw) * 8);
        __builtin_amdgcn_s_setprio(1);
#pragma unroll
        for (int nt = 0; nt < 4; ++nt)
          oacc[mt][nt] = __builtin_amdgcn_mfma_f32_16x16x32_bf16(pf, vf[nt], oacc[mt][nt], 0, 0, 0);
        lacc[mt] = __builtin_amdgcn_mfma_f32_16x16x32_bf16(pf, onesf, lacc[mt], 0, 0, 0);
        __builtin_amdgcn_s_setprio(0);
      }
    }
  }

  // lacc[mt][r] = rowsum for q-row (quad*4+r) of tile mt — same indexing as oacc rows
  float linv[2][4];
#pragma unroll
  for (int mt = 0; mt < 2; ++mt)
#pragma unroll
    for (int r = 0; r < 4; ++r) linv[mt][r] = 1.f / lacc[mt][r];

#pragma unroll
  for (int mt = 0; mt < 2; ++mt)
#pragma unroll
    for (int nt = 0; nt < 4; ++nt)
#pragma unroll
      for (int r = 0; r < 4; ++r) {
        size_t row = rowB + (size_t)(q0 + w * 32 + mt * 16 + quad * 4 + r);
        size_t col = (size_t)h * 64 + nt * 16 + l15;
        out[row * 2048 + col] = f2bf(oacc[mt][nt][r] * linv[mt][r]);
      }
}

extern "C" void kernel_launch(void* const* d_in, const int* in_sizes, int n_in, void* d_out,
                              int out_size, void* d_ws, size_t ws_size, hipStream_t stream) {
  const float* x = (const float*)d_in[0];
  const float* fcos = (const float*)d_in[1];
  const float* fsin = (const float*)d_in[2];
  const float* wq = (const float*)d_in[3];
  const float* wk = (const float*)d_in[4];
  const float* wv = (const float*)d_in[5];
  const float* wo = (const float*)d_in[6];

  char* ws = (char*)d_ws;
  unsigned short* xb = (unsigned short*)ws;                       // 4096x2048 bf16  @0      (16 MiB)
  unsigned short* wt = (unsigned short*)(ws + 16777216ull);       // 3072x2048 bf16  @16 MiB (12 MiB)
  unsigned short* wot = (unsigned short*)(ws + 29360128ull);      // 2048x2048 bf16  @28 MiB (8 MiB)
  unsigned short* qkv = (unsigned short*)(ws + 37748736ull);      // 4096x2560 bf16  @36 MiB (20 MiB)
  unsigned short* attno = (unsigned short*)(ws + 58720256ull);    // 4096x2048 bf16  @56 MiB (16 MiB)
  unsigned short* vt = (unsigned short*)(ws + 75497472ull);       // 16x64x2048 bf16 @72 MiB (4 MiB)
  // total: 76 MiB

  prep<<<dim3(64, 64, 5), 256, 0, stream>>>(x, wq, wk, wv, wo, xb, wt, wot);
  // QKV GEMM over N=3072 concat [wq|wk|wv]; Q -> qkv, K -> qkv with fused RoPE, V -> vt transposed
  gemm_bt64<1><<<dim3(24, 32), 256, 0, stream>>>(xb, wt, qkv, 2048, 2560, vt, fcos, fsin);
  flash_attn<<<dim3(8, 32, 2), 512, 0, stream>>>(qkv, vt, fcos, fsin, attno);
  gemm_bt64<0><<<dim3(16, 32), 256, 0, stream>>>(attno, wot, d_out, 2048, 2048, nullptr, nullptr, nullptr);
}